// Round 4
// baseline (382.728 us; speedup 1.0000x reference)
//
#include <hip/hip_runtime.h>

// int4 weight-only quantized GEMV: out[n] = sum_k A[k] * W[n,k]
//   W[n,k] = (nib(B)[n,k] - 8) * scale[n, k/32] + zero[n, k/32]
// M=1, K=8192, N=16384, GROUP=32.
// Dtypes: A [8192] f32, B [N, K/2] int32 (1 byte payload, low nibble = even k),
// SZ [N, 256, 2] f32, out [N] f32.
//
// R12: five structures (R5-R8, R11) all plateau at 2.9-3.0 TB/s despite
// >100 KB/CU burst-outstanding (10x Little's-law need) -> per-CU HW funnel
// on the global->VGPR read-return path (~11.4 GB/s/CU * 256 = 2.92 TB/s).
// This version switches B and SZ to the ONLY untried read path:
// global_load_lds (DMA direct to LDS, bypasses VGPR return; m97 GEMM
// sustains ~108 GB/s/CU on it). 4-deep LDS ring, 1 row (16 KB) per tile,
// depth-2 prefetch, counted-vmcnt raw barriers (T4) -- __syncthreads would
// drain the prefetch (that's what kept R11 at R8's level). Every wave
// issues exactly 3 gload_lds per tile (2x B@16B + 1x SZ@4B) -> static
// per-wave vmcnt waits 6/3/0 are exact. No global stores in the loop
// (results parked in LDS red2, written once at the end).

#define TPB   512
#define TILES 32          // rows per block, 1 row per tile
#define NBUF  4

typedef int   ivec4 __attribute__((ext_vector_type(4)));
typedef float fvec2 __attribute__((ext_vector_type(2)));

__global__ __launch_bounds__(TPB, 4) void gemv_w4lds(
    const float4* __restrict__ A4,   // 8192 f32 = 2048 float4
    const int*    __restrict__ B,    // [N, 4096] int32 (1 byte payload)
    const float*  __restrict__ SZ,   // [N, 256, 2] f32
    float* __restrict__ out,         // [N] f32
    int N)
{
    const int t    = threadIdx.x;
    const int w    = t >> 6;          // wave id 0..7 (uniform per wave)
    const int lane = t & 63;
    const int row0 = blockIdx.x * TILES;
    const int g0   = t >> 2;          // quant group of ivec4 t

    __shared__ ivec4 bbuf[NBUF][1024];   // 4 x 16 KB  (one B row per buf)
    __shared__ fvec2 szbuf[NBUF][256];   // 4 x 2 KB   (one SZ row per buf)
    __shared__ float red2[TILES][8];     // 1 KB: per-row per-wave partials

    // ---- A -> regs once (thread t covers ivec4 t and t+512 of every row) ---
    float a[2][8];
    float sA[2];
#pragma unroll
    for (int j = 0; j < 2; ++j) {
        const int i = t + 512 * j;
        const float4 x = A4[2 * i];
        const float4 y = A4[2 * i + 1];
        a[j][0] = x.x; a[j][1] = x.y; a[j][2] = x.z; a[j][3] = x.w;
        a[j][4] = y.x; a[j][5] = y.y; a[j][6] = y.z; a[j][7] = y.w;
        sA[j] = ((x.x + x.y) + (x.z + x.w)) + ((y.x + y.y) + (y.z + y.w));
    }

    // ---- stage row (row0+T) into ring slot T&3: exactly 3 gload_lds/wave ---
    auto stage = [&](int T) {
        const int p = T & (NBUF - 1);
        const char* gb = (const char*)B + (size_t)(row0 + T) * 16384;
        // B: 16 KB = 16 chunks of 1 KB; wave w takes chunks w and w+8.
        // LDS dest is wave-uniform base + lane*16 (HW rule, m104).
        __builtin_amdgcn_global_load_lds(
            (const unsigned int*)(gb + w * 1024 + lane * 16),
            (unsigned int*)&bbuf[p][w * 64], 16, 0, 0);
        __builtin_amdgcn_global_load_lds(
            (const unsigned int*)(gb + (w + 8) * 1024 + lane * 16),
            (unsigned int*)&bbuf[p][(w + 8) * 64], 16, 0, 0);
        // SZ row: 2 KB = 8 chunks of 256 B; wave w takes chunk w (4 B/lane).
        const char* gs = (const char*)SZ + (size_t)(row0 + T) * 2048;
        __builtin_amdgcn_global_load_lds(
            (const unsigned int*)(gs + w * 256 + lane * 4),
            (unsigned int*)&szbuf[p][0] + w * 64, 4, 0, 0);
    };

    // ---- prologue: depth-2 prefetch (units 0,1,2 in flight = 9 vmem ops) ---
    stage(0); stage(1); stage(2);

#pragma unroll
    for (int T = 0; T < TILES; ++T) {
        // wait own unit T (3 ops), leave newer units in flight
        if (T < TILES - 2)       asm volatile("s_waitcnt vmcnt(6)" ::: "memory");
        else if (T == TILES - 2) asm volatile("s_waitcnt vmcnt(3)" ::: "memory");
        else                     asm volatile("s_waitcnt vmcnt(0)" ::: "memory");
        __builtin_amdgcn_s_barrier();          // all waves' unit T staged
        __builtin_amdgcn_sched_barrier(0);

        // ---- consume tile T from LDS ----
        const int p = T & (NBUF - 1);
        const ivec4 b0 = bbuf[p][t];           // ds_read_b128, conflict-free
        const ivec4 b1 = bbuf[p][512 + t];
        const fvec2 s0 = szbuf[p][g0];         // ds_read_b64, 4-lane broadcast
        const fvec2 s1 = szbuf[p][128 + g0];

        float v = 0.0f;
        {
            const int c0 = b0[0], c1 = b0[1], c2 = b0[2], c3 = b0[3];
            float dot = 0.0f;
            dot = fmaf(a[0][0], (float)(c0 & 0xF),        dot);
            dot = fmaf(a[0][1], (float)((c0 >> 4) & 0xF), dot);
            dot = fmaf(a[0][2], (float)(c1 & 0xF),        dot);
            dot = fmaf(a[0][3], (float)((c1 >> 4) & 0xF), dot);
            dot = fmaf(a[0][4], (float)(c2 & 0xF),        dot);
            dot = fmaf(a[0][5], (float)((c2 >> 4) & 0xF), dot);
            dot = fmaf(a[0][6], (float)(c3 & 0xF),        dot);
            dot = fmaf(a[0][7], (float)((c3 >> 4) & 0xF), dot);
            v = fmaf(s0[0], dot, v);
            v = fmaf(fmaf(-8.0f, s0[0], s0[1]), sA[0], v);
        }
        {
            const int c0 = b1[0], c1 = b1[1], c2 = b1[2], c3 = b1[3];
            float dot = 0.0f;
            dot = fmaf(a[1][0], (float)(c0 & 0xF),        dot);
            dot = fmaf(a[1][1], (float)((c0 >> 4) & 0xF), dot);
            dot = fmaf(a[1][2], (float)(c1 & 0xF),        dot);
            dot = fmaf(a[1][3], (float)((c1 >> 4) & 0xF), dot);
            dot = fmaf(a[1][4], (float)(c2 & 0xF),        dot);
            dot = fmaf(a[1][5], (float)((c2 >> 4) & 0xF), dot);
            dot = fmaf(a[1][6], (float)(c3 & 0xF),        dot);
            dot = fmaf(a[1][7], (float)((c3 >> 4) & 0xF), dot);
            v = fmaf(s1[0], dot, v);
            v = fmaf(fmaf(-8.0f, s1[0], s1[1]), sA[1], v);
        }

        // wave-local reduce; park partial in LDS (no global store in loop)
#pragma unroll
        for (int off = 32; off > 0; off >>= 1)
            v += __shfl_down(v, off, 64);
        if (lane == 0) red2[T][w] = v;

        // drain this wave's ds ops, then gate the ring-slot overwrite
        asm volatile("s_waitcnt lgkmcnt(0)" ::: "memory");
        __builtin_amdgcn_sched_barrier(0);
        __builtin_amdgcn_s_barrier();

        if (T + 3 < TILES) stage(T + 3);
    }

    // ---- epilogue: one coalesced store pass ----
    __syncthreads();
    if (t < TILES) {
        const int n = row0 + t;
        if (n < N) {
            float v = 0.0f;
#pragma unroll
            for (int w2 = 0; w2 < 8; ++w2) v += red2[t][w2];
            out[n] = v;
        }
    }
}

extern "C" void kernel_launch(void* const* d_in, const int* in_sizes, int n_in,
                              void* d_out, int out_size, void* d_ws, size_t ws_size,
                              hipStream_t stream) {
    const float4* A4 = (const float4*)d_in[0];   // f32[8192]
    const int*    B  = (const int*)d_in[1];      // int32[N, 4096]
    const float*  SZ = (const float*)d_in[2];    // f32[N, 256, 2]
    float* out = (float*)d_out;                  // f32[N]

    const int N = out_size;                      // 16384
    gemv_w4lds<<<N / TILES, TPB, 0, stream>>>(A4, B, SZ, out, N);
}